// Round 3
// baseline (651.782 us; speedup 1.0000x reference)
//
#include <hip/hip_runtime.h>
#include <stdint.h>

// ---------------- workspace layout (uint32 words), per matrix ----------------
#define OFF_SH     0u        // 16384-bin sample histogram (bits 30..17)
#define OFF_H1     16384u    // 2048 bins, bits 30..21 (candidates only)
#define OFF_H2     18432u    // 2048 bins, bits 20..10
#define OFF_H3     20480u    // 1024 bins, bits 9..0
#define OFF_G      21504u    // speculative lower bound (bit pattern)
#define OFF_CNT    21505u    // candidate count
#define OFF_PREFIX 21506u
#define OFF_RANK   21507u
#define OFF_T      21508u
#define OFF_C      21509u
#define OFF_TCNT   21510u    // tie-candidate count
#define OFF_TBUF   21512u    // tie candidates (idx,u) pairs
#define TCAP       8192u     // measured ~1-4K matches of the 21-bit prefix
#define MAT_WORDS  (21512u + 2u * TCAP)   // 37896 words ~148KB; x2 ~296KB ws
#define INIT_WORDS 21512u
#define CAPBUF     8388608u  // candidate entries per matrix; 64MB half of d_out
// candidate buffer lives in d_out: matrix m at out_u32 + m*16777216 (uint2 pairs).
// It is fully consumed by the small select kernels before mask_k overwrites d_out.

__global__ void init_k(uint32_t* __restrict__ ws) {
  uint32_t i = blockIdx.x * blockDim.x + threadIdx.x;
  if (i < INIT_WORDS) { ws[i] = 0u; ws[MAT_WORDS + i] = 0u; }
}

// Sample 65536 floats per matrix (256 chunks of 64 float4, coalesced per wave),
// histogram bits 30..17 (16384 bins). ~1MB traffic.
__global__ void sample_k(const float* __restrict__ A, const float* __restrict__ B,
                         uint32_t* __restrict__ ws, int nvec) {
  const int m = blockIdx.y;
  const float4* __restrict__ src = (const float4*)(m == 0 ? A : B);
  uint32_t* W = ws + (size_t)m * MAT_WORDS;
  __shared__ uint32_t sh[16384];                 // 64KB
  for (int i = threadIdx.x; i < 16384; i += blockDim.x) sh[i] = 0u;
  __syncthreads();
  const int w = threadIdx.x >> 6, lane = threadIdx.x & 63;
  const int cstride = nvec / 256;                // chunk stride in float4
  for (int it = 0; it < 4; it++) {
    int chunk = blockIdx.x * 16 + it * 4 + w;    // 0..255, each distinct
    int fi = chunk * cstride + lane;
    if (fi < nvec) {
      float4 f = src[fi];
      const float v[4] = {f.x, f.y, f.z, f.w};
#pragma unroll
      for (int c = 0; c < 4; c++) {
        uint32_t u = __float_as_uint(v[c]) & 0x7fffffffu;
        atomicAdd(&sh[u >> 17], 1u);
      }
    }
  }
  __syncthreads();
  for (int b = threadIdx.x; b < 16384; b += blockDim.x)
    if (sh[b]) atomicAdd(&W[OFF_SH + b], sh[b]);
}

// Pick G = highest bin edge with sample-count(>= edge) >= need (~13% of samples).
// True keep fraction is 10%; 3% margin = ~25 sigma at 65536 samples -> G <= T.
__global__ void scanG_k(uint32_t* __restrict__ ws, uint32_t need) {
  const int m = blockIdx.x;
  uint32_t* W = ws + (size_t)m * MAT_WORDS;
  __shared__ uint32_t ps[256];
  __shared__ int sbest;
  const int t = threadIdx.x;
  if (t == 0) sbest = -1;
  uint32_t sum = 0u;
  for (int k = 0; k < 64; k++) sum += W[OFF_SH + t * 64 + k];
  ps[t] = sum;
  __syncthreads();
  for (int off = 1; off < 256; off <<= 1) {
    uint32_t v = (t >= off) ? ps[t - off] : 0u;
    __syncthreads();
    ps[t] += v;
    __syncthreads();
  }
  uint32_t total = ps[255];
  uint32_t cum = ps[t] - sum;                    // exclusive prefix (bins < t*64)
  int best = -1;
  for (int k = 0; k < 64; k++) {
    int b = t * 64 + k;
    if (total - cum >= need) best = b;           // suffix(b) >= need; monotone
    cum += W[OFF_SH + b];
  }
  if (best >= 0) atomicMax(&sbest, best);
  __syncthreads();
  if (t == 0) W[OFF_G] = (sbest >= 0) ? ((uint32_t)sbest << 17) : 0u;
}

// THE single full-data select pass: compact (idx,u) with u >= G into d_out
// scratch, and histogram candidates' bits 30..21. Block-aggregated slot alloc.
__global__ void pass1_k(const float* __restrict__ A, const float* __restrict__ B,
                        uint32_t* __restrict__ ws, uint32_t* __restrict__ outbuf,
                        int nvec) {
  const int m = blockIdx.y;
  const float4* __restrict__ src = (const float4*)(m == 0 ? A : B);
  uint32_t* W = ws + (size_t)m * MAT_WORDS;
  uint2* __restrict__ buf = (uint2*)(outbuf + (size_t)m * 16777216u);
  __shared__ uint32_t h[2048 * 4];
  __shared__ uint32_t lcnt, lbase;
  for (int i = threadIdx.x; i < 2048 * 4; i += blockDim.x) h[i] = 0u;
  const uint32_t G = W[OFF_G];
  __syncthreads();
  const uint32_t sub = threadIdx.x & 3u;
  int idx0 = blockIdx.x * blockDim.x + threadIdx.x;
  int stride = gridDim.x * blockDim.x;
  for (int i = idx0; i < nvec; i += stride) {
    float4 f = src[i];
    const float v[4] = {f.x, f.y, f.z, f.w};
    uint32_t cu[4], ci[4], tc = 0u;
#pragma unroll
    for (int c = 0; c < 4; c++) {
      uint32_t u = __float_as_uint(v[c]) & 0x7fffffffu;
      if (u >= G) {
        cu[tc] = u; ci[tc] = (uint32_t)i * 4u + (uint32_t)c; tc++;
        atomicAdd(&h[(u >> 21) * 4u + sub], 1u);
      }
    }
    if (threadIdx.x == 0) lcnt = 0u;
    __syncthreads();
    uint32_t off = tc ? atomicAdd(&lcnt, tc) : 0u;
    __syncthreads();
    if (threadIdx.x == 0) lbase = lcnt ? atomicAdd(&W[OFF_CNT], lcnt) : 0u;
    __syncthreads();
    uint32_t base = lbase + off;
    for (uint32_t k = 0; k < tc; k++) {
      uint32_t s = base + k;
      if (s < CAPBUF) buf[s] = make_uint2(ci[k], cu[k]);
    }
  }
  __syncthreads();
  for (int b = threadIdx.x; b < 2048; b += blockDim.x) {
    uint32_t s = h[b * 4] + h[b * 4 + 1] + h[b * 4 + 2] + h[b * 4 + 3];
    if (s) atomicAdd(&W[OFF_H1 + b], s);
  }
}

// Scan H1: rank within candidates r' = cnt - keep (all non-candidates < G <= T).
__global__ void scan1_k(uint32_t* __restrict__ ws, uint32_t keep) {
  const int m = blockIdx.x;
  uint32_t* W = ws + (size_t)m * MAT_WORDS;
  __shared__ uint32_t h[2048];
  __shared__ uint32_t ps[256];
  const int t = threadIdx.x;
  uint32_t cnt = W[OFF_CNT]; if (cnt > CAPBUF) cnt = CAPBUF;
  uint32_t r = cnt - keep;
  uint32_t s = 0u;
  for (int k = 0; k < 8; k++) {
    int b = t * 8 + k;
    uint32_t v = W[OFF_H1 + b];
    h[b] = v; s += v;
  }
  ps[t] = s;
  __syncthreads();
  for (int off = 1; off < 256; off <<= 1) {
    uint32_t v = (t >= off) ? ps[t - off] : 0u;
    __syncthreads();
    ps[t] += v;
    __syncthreads();
  }
  uint32_t base = (t == 0) ? 0u : ps[t - 1];
  for (int k = 0; k < 8; k++) {
    int b = t * 8 + k;
    uint32_t c = h[b];
    if (r >= base && r < base + c) {
      W[OFF_PREFIX] = (uint32_t)b << 21;
      W[OFF_RANK]   = r - base;
    }
    base += c;
  }
}

// Buffer pass: histogram bits 20..10 of entries matching the 11-bit prefix.
__global__ void hist2b_k(uint32_t* __restrict__ ws, const uint32_t* __restrict__ outbuf) {
  const int m = blockIdx.y;
  uint32_t* W = ws + (size_t)m * MAT_WORDS;
  const uint2* __restrict__ buf = (const uint2*)(outbuf + (size_t)m * 16777216u);
  __shared__ uint32_t h[2048 * 4];
  for (int i = threadIdx.x; i < 2048 * 4; i += blockDim.x) h[i] = 0u;
  uint32_t cnt = W[OFF_CNT]; if (cnt > CAPBUF) cnt = CAPBUF;
  uint32_t p21 = W[OFF_PREFIX] >> 21;
  __syncthreads();
  const uint32_t sub = threadIdx.x & 3u;
  for (uint32_t e = blockIdx.x * blockDim.x + threadIdx.x; e < cnt;
       e += gridDim.x * blockDim.x) {
    uint2 v = buf[e];
    if ((v.y >> 21) == p21) atomicAdd(&h[((v.y >> 10) & 2047u) * 4u + sub], 1u);
  }
  __syncthreads();
  for (int b = threadIdx.x; b < 2048; b += blockDim.x) {
    uint32_t s = h[b * 4] + h[b * 4 + 1] + h[b * 4 + 2] + h[b * 4 + 3];
    if (s) atomicAdd(&W[OFF_H2 + b], s);
  }
}

__global__ void scan2_k(uint32_t* __restrict__ ws) {
  const int m = blockIdx.x;
  uint32_t* W = ws + (size_t)m * MAT_WORDS;
  __shared__ uint32_t h[2048];
  __shared__ uint32_t ps[256];
  const int t = threadIdx.x;
  uint32_t r = W[OFF_RANK];
  uint32_t prefix = W[OFF_PREFIX];
  uint32_t s = 0u;
  for (int k = 0; k < 8; k++) {
    int b = t * 8 + k;
    uint32_t v = W[OFF_H2 + b];
    h[b] = v; s += v;
  }
  ps[t] = s;
  __syncthreads();
  for (int off = 1; off < 256; off <<= 1) {
    uint32_t v = (t >= off) ? ps[t - off] : 0u;
    __syncthreads();
    ps[t] += v;
    __syncthreads();
  }
  uint32_t base = (t == 0) ? 0u : ps[t - 1];
  for (int k = 0; k < 8; k++) {
    int b = t * 8 + k;
    uint32_t c = h[b];
    if (r >= base && r < base + c) {
      W[OFF_PREFIX] = prefix | ((uint32_t)b << 10);
      W[OFF_RANK]   = r - base;
    }
    base += c;
  }
}

// Buffer pass: low-10-bit histogram + exact tie-candidate collection.
__global__ void pass3b_k(uint32_t* __restrict__ ws, const uint32_t* __restrict__ outbuf) {
  const int m = blockIdx.y;
  uint32_t* W = ws + (size_t)m * MAT_WORDS;
  const uint2* __restrict__ buf = (const uint2*)(outbuf + (size_t)m * 16777216u);
  __shared__ uint32_t h[1024];
  for (int i = threadIdx.x; i < 1024; i += blockDim.x) h[i] = 0u;
  uint32_t cnt = W[OFF_CNT]; if (cnt > CAPBUF) cnt = CAPBUF;
  uint32_t p10 = W[OFF_PREFIX] >> 10;
  __syncthreads();
  for (uint32_t e = blockIdx.x * blockDim.x + threadIdx.x; e < cnt;
       e += gridDim.x * blockDim.x) {
    uint2 v = buf[e];
    if ((v.y >> 10) == p10) {
      atomicAdd(&h[v.y & 1023u], 1u);
      uint32_t slot = atomicAdd(&W[OFF_TCNT], 1u);   // ~1-4K total per matrix
      if (slot < TCAP) { W[OFF_TBUF + 2u * slot] = v.x; W[OFF_TBUF + 2u * slot + 1u] = v.y; }
    }
  }
  __syncthreads();
  for (int b = threadIdx.x; b < 1024; b += blockDim.x)
    if (h[b]) atomicAdd(&W[OFF_H3 + b], h[b]);
}

// Fused: scan H3 -> T, then tie-resolve entirely in LDS (verified R1/R2 logic).
__global__ void scan3tie_k(uint32_t* __restrict__ ws) {
  const int m = blockIdx.x;
  uint32_t* W = ws + (size_t)m * MAT_WORDS;
  __shared__ uint32_t h[1024];
  __shared__ uint32_t ps[256];
  __shared__ uint32_t sT, sTarget;
  __shared__ uint32_t tie_idx[1024];
  __shared__ uint32_t tie_n;
  const int t = threadIdx.x;
  uint32_t r = W[OFF_RANK];
  uint32_t prefix = W[OFF_PREFIX];
  uint32_t cnt = W[OFF_TCNT]; if (cnt > TCAP) cnt = TCAP;
  if (t == 0) tie_n = 0u;
  uint32_t s = 0u;
  for (int k = 0; k < 4; k++) {
    int b = t * 4 + k;
    uint32_t v = W[OFF_H3 + b];
    h[b] = v; s += v;
  }
  ps[t] = s;
  __syncthreads();
  for (int off = 1; off < 256; off <<= 1) {
    uint32_t v = (t >= off) ? ps[t - off] : 0u;
    __syncthreads();
    ps[t] += v;
    __syncthreads();
  }
  uint32_t base = (t == 0) ? 0u : ps[t - 1];
  for (int k = 0; k < 4; k++) {
    int b = t * 4 + k;
    uint32_t c = h[b];
    if (r >= base && r < base + c) { sT = prefix | (uint32_t)b; sTarget = r - base; }
    base += c;
  }
  __syncthreads();
  const uint32_t T = sT, target = sTarget;       // target = p; q = E - p get 1
  for (uint32_t c2 = t; c2 < cnt; c2 += 256u) {
    if (W[OFF_TBUF + 2u * c2 + 1u] == T) {
      uint32_t slot = atomicAdd(&tie_n, 1u);
      if (slot < 1024u) tie_idx[slot] = W[OFF_TBUF + 2u * c2];
    }
  }
  __syncthreads();
  uint32_t E2 = tie_n; if (E2 > 1024u) E2 = 1024u;
  for (uint32_t c2 = t; c2 < E2; c2 += 256u) {
    uint32_t xi = tie_idx[c2];
    uint32_t lt = 0u;
    for (uint32_t k2 = 0; k2 < E2; k2++) lt += (tie_idx[k2] < xi) ? 1u : 0u;
    if (lt == target) W[OFF_C] = xi;             // p-th smallest index = cutoff
  }
  if (t == 0) W[OFF_T] = T;
}

__global__ void mask_k(const float* __restrict__ A, const float* __restrict__ B,
                       float* __restrict__ out, const uint32_t* __restrict__ ws,
                       int nvec, int n) {
  const int m = blockIdx.y;
  const float4* __restrict__ src = (const float4*)(m == 0 ? A : B);
  float4* __restrict__ dst = (float4*)(out + (size_t)m * (size_t)n);
  const uint32_t* W = ws + (size_t)m * MAT_WORDS;
  const uint32_t T = W[OFF_T];
  const uint32_t C = W[OFF_C];
  int idx0 = blockIdx.x * blockDim.x + threadIdx.x;
  int stride = gridDim.x * blockDim.x;
  for (int i = idx0; i < nvec; i += stride) {
    float4 f = src[i];
    const float v[4] = {f.x, f.y, f.z, f.w};
    float r[4];
#pragma unroll
    for (int c = 0; c < 4; c++) {
      uint32_t u = __float_as_uint(v[c]) & 0x7fffffffu;
      uint32_t idx = (uint32_t)i * 4u + (uint32_t)c;
      r[c] = (u > T || (u == T && idx >= C)) ? 1.0f : 0.0f;
    }
    dst[i] = make_float4(r[0], r[1], r[2], r[3]);
  }
}

extern "C" void kernel_launch(void* const* d_in, const int* in_sizes, int n_in,
                              void* d_out, int out_size, void* d_ws, size_t ws_size,
                              hipStream_t stream) {
  const float* A = (const float*)d_in[0];
  const float* B = (const float*)d_in[1];
  float* out = (float*)d_out;
  uint32_t* ws = (uint32_t*)d_ws;
  uint32_t* outbuf = (uint32_t*)d_out;       // scratch until mask_k overwrites it
  const int n = in_sizes[0];                 // 16777216 per matrix
  const int nvec = n / 4;
  const uint32_t j = (uint32_t)((1.0 - 0.1) * (double)n);  // Python int((1-k)*n)
  const uint32_t keep = (uint32_t)n - j;                   // 1677722
  const uint32_t samples = 65536u;
  const uint32_t need = (13u * samples) / 100u;            // 13% quantile edge

  init_k<<<(INIT_WORDS + 255) / 256, 256, 0, stream>>>(ws);
  sample_k<<<dim3(16, 2), 256, 0, stream>>>(A, B, ws, nvec);
  scanG_k<<<2, 256, 0, stream>>>(ws, need);
  pass1_k<<<dim3(1024, 2), 256, 0, stream>>>(A, B, ws, outbuf, nvec);
  scan1_k<<<2, 256, 0, stream>>>(ws, keep);
  hist2b_k<<<dim3(128, 2), 256, 0, stream>>>(ws, outbuf);
  scan2_k<<<2, 256, 0, stream>>>(ws);
  pass3b_k<<<dim3(128, 2), 256, 0, stream>>>(ws, outbuf);
  scan3tie_k<<<2, 256, 0, stream>>>(ws);
  mask_k<<<dim3(2048, 2), 256, 0, stream>>>(A, B, out, ws, nvec, n);
}

// Round 4
// 378.372 us; speedup vs baseline: 1.7226x; 1.7226x over previous
//
#include <hip/hip_runtime.h>
#include <stdint.h>

// ---------------- workspace layout (uint32 words), per matrix ----------------
#define OFF_SH     0u        // 16384-bin sample histogram (bits 30..17)
#define OFF_H1     16384u    // 2048 bins, bits 30..21 (candidates only)
#define OFF_H2     18432u    // 2048 bins, bits 20..10
#define OFF_H3     20480u    // 1024 bins, bits 9..0
#define OFF_G      21504u    // speculative lower bound (bit pattern)
#define OFF_CNT    21505u    // total candidate count
#define OFF_PREFIX 21506u
#define OFF_RANK   21507u
#define OFF_T      21508u
#define OFF_C      21509u
#define OFF_TCNT   21510u    // tie-candidate count
#define OFF_BCNT   21512u    // 512 per-segment counts
#define OFF_TBUF   22024u    // tie candidates (idx,u) pairs
#define TCAP       8192u
#define MAT_WORDS  (22024u + 2u * TCAP)   // 38408 words ~150KB; x2 ~300KB ws
#define INIT_WORDS 22024u
#define NB         512       // compact blocks per matrix (= segments)
#define SEGCAP     16384u    // uint2 entries per segment; expected ~4460 -> 3.7x headroom
// Segment buffer lives in d_out: matrix m at out_u32 + m*16777216 words.
// 512 * 16384 * 2 words = exactly the 64MiB half. Fully consumed before mask_k
// overwrites d_out.

__global__ void init_k(uint32_t* __restrict__ ws) {
  uint32_t i = blockIdx.x * blockDim.x + threadIdx.x;
  if (i < INIT_WORDS) { ws[i] = 0u; ws[MAT_WORDS + i] = 0u; }
}

// Sample 65536 floats per matrix, histogram bits 30..17. ~1MB traffic.
__global__ void sample_k(const float* __restrict__ A, const float* __restrict__ B,
                         uint32_t* __restrict__ ws, int nvec) {
  const int m = blockIdx.y;
  const float4* __restrict__ src = (const float4*)(m == 0 ? A : B);
  uint32_t* W = ws + (size_t)m * MAT_WORDS;
  __shared__ uint32_t sh[16384];
  for (int i = threadIdx.x; i < 16384; i += blockDim.x) sh[i] = 0u;
  __syncthreads();
  const int w = threadIdx.x >> 6, lane = threadIdx.x & 63;
  const int cstride = nvec / 256;
  for (int it = 0; it < 4; it++) {
    int chunk = blockIdx.x * 16 + it * 4 + w;    // 0..255 distinct
    int fi = chunk * cstride + lane;
    if (fi < nvec) {
      float4 f = src[fi];
      const float v[4] = {f.x, f.y, f.z, f.w};
#pragma unroll
      for (int c = 0; c < 4; c++) {
        uint32_t u = __float_as_uint(v[c]) & 0x7fffffffu;
        atomicAdd(&sh[u >> 17], 1u);
      }
    }
  }
  __syncthreads();
  for (int b = threadIdx.x; b < 16384; b += blockDim.x)
    if (sh[b]) atomicAdd(&W[OFF_SH + b], sh[b]);
}

// G = highest bin edge with sample-count(>= edge) >= need (~13% of samples).
// True keep = 10%; 3% margin = ~25 sigma at 65536 samples -> G <= T certain.
__global__ void scanG_k(uint32_t* __restrict__ ws, uint32_t need) {
  const int m = blockIdx.x;
  uint32_t* W = ws + (size_t)m * MAT_WORDS;
  __shared__ uint32_t ps[256];
  __shared__ int sbest;
  const int t = threadIdx.x;
  if (t == 0) sbest = -1;
  uint32_t sum = 0u;
  for (int k = 0; k < 64; k++) sum += W[OFF_SH + t * 64 + k];
  ps[t] = sum;
  __syncthreads();
  for (int off = 1; off < 256; off <<= 1) {
    uint32_t v = (t >= off) ? ps[t - off] : 0u;
    __syncthreads();
    ps[t] += v;
    __syncthreads();
  }
  uint32_t total = ps[255];
  uint32_t cum = ps[t] - sum;
  int best = -1;
  for (int k = 0; k < 64; k++) {
    int b = t * 64 + k;
    if (total - cum >= need) best = b;
    cum += W[OFF_SH + b];
  }
  if (best >= 0) atomicMax(&sbest, best);
  __syncthreads();
  if (t == 0) W[OFF_G] = (sbest >= 0) ? ((uint32_t)sbest << 17) : 0u;
}

// THE single full-data pass: compact (idx,u) with u >= G into this block's
// PRIVATE segment. R2-proven pattern: LDS counter, no in-loop barriers, no
// in-loop global atomics, no histogram (level-1 hist moved to buffer pass).
__global__ void compact_k(const float* __restrict__ A, const float* __restrict__ B,
                          uint32_t* __restrict__ ws, uint32_t* __restrict__ outbuf,
                          int nvec) {
  const int m = blockIdx.y;
  const float4* __restrict__ src = (const float4*)(m == 0 ? A : B);
  uint32_t* W = ws + (size_t)m * MAT_WORDS;
  uint2* __restrict__ seg = (uint2*)(outbuf + (size_t)m * 16777216u) + (size_t)blockIdx.x * SEGCAP;
  __shared__ uint32_t segn;
  if (threadIdx.x == 0) segn = 0u;
  const uint32_t G = W[OFF_G];
  __syncthreads();
  int idx0 = blockIdx.x * blockDim.x + threadIdx.x;
  int stride = gridDim.x * blockDim.x;           // 512*256 = 131072
  for (int i = idx0; i < nvec; i += stride) {    // 32 iterations
    float4 f = src[i];
    const float v[4] = {f.x, f.y, f.z, f.w};
    uint32_t cu[4], ci[4], tc = 0u;
#pragma unroll
    for (int c = 0; c < 4; c++) {
      uint32_t u = __float_as_uint(v[c]) & 0x7fffffffu;
      if (u >= G) { cu[tc] = u; ci[tc] = (uint32_t)i * 4u + (uint32_t)c; tc++; }
    }
    if (tc) {
      uint32_t s = atomicAdd(&segn, tc);
      for (uint32_t k = 0; k < tc; k++)
        if (s + k < SEGCAP) seg[s + k] = make_uint2(ci[k], cu[k]);
    }
  }
  __syncthreads();
  if (threadIdx.x == 0) {
    uint32_t c = segn; if (c > SEGCAP) c = SEGCAP;
    W[OFF_BCNT + blockIdx.x] = c;
    atomicAdd(&W[OFF_CNT], c);                   // once per block
  }
}

// Buffer pass: histogram bits 30..21 of all candidates. One block per segment.
__global__ void hist1b_k(uint32_t* __restrict__ ws, const uint32_t* __restrict__ outbuf) {
  const int m = blockIdx.y;
  uint32_t* W = ws + (size_t)m * MAT_WORDS;
  const uint2* __restrict__ seg = (const uint2*)(outbuf + (size_t)m * 16777216u) + (size_t)blockIdx.x * SEGCAP;
  __shared__ uint32_t h[2048 * 4];
  for (int i = threadIdx.x; i < 2048 * 4; i += blockDim.x) h[i] = 0u;
  uint32_t n = W[OFF_BCNT + blockIdx.x];
  __syncthreads();
  const uint32_t sub = threadIdx.x & 3u;
  for (uint32_t e = threadIdx.x; e < n; e += blockDim.x) {
    uint2 v = seg[e];
    atomicAdd(&h[(v.y >> 21) * 4u + sub], 1u);
  }
  __syncthreads();
  for (int b = threadIdx.x; b < 2048; b += blockDim.x) {
    uint32_t s = h[b * 4] + h[b * 4 + 1] + h[b * 4 + 2] + h[b * 4 + 3];
    if (s) atomicAdd(&W[OFF_H1 + b], s);
  }
}

// Scan H1. Rank within candidates: r = cnt - keep (non-candidates < G <= T).
__global__ void scan1_k(uint32_t* __restrict__ ws, uint32_t keep) {
  const int m = blockIdx.x;
  uint32_t* W = ws + (size_t)m * MAT_WORDS;
  __shared__ uint32_t h[2048];
  __shared__ uint32_t ps[256];
  const int t = threadIdx.x;
  uint32_t cnt = W[OFF_CNT];
  uint32_t r = cnt - keep;
  uint32_t s = 0u;
  for (int k = 0; k < 8; k++) {
    int b = t * 8 + k;
    uint32_t v = W[OFF_H1 + b];
    h[b] = v; s += v;
  }
  ps[t] = s;
  __syncthreads();
  for (int off = 1; off < 256; off <<= 1) {
    uint32_t v = (t >= off) ? ps[t - off] : 0u;
    __syncthreads();
    ps[t] += v;
    __syncthreads();
  }
  uint32_t base = (t == 0) ? 0u : ps[t - 1];
  for (int k = 0; k < 8; k++) {
    int b = t * 8 + k;
    uint32_t c = h[b];
    if (r >= base && r < base + c) {
      W[OFF_PREFIX] = (uint32_t)b << 21;
      W[OFF_RANK]   = r - base;
    }
    base += c;
  }
}

// Buffer pass: bits 20..10 of entries matching the 11-bit prefix.
__global__ void hist2b_k(uint32_t* __restrict__ ws, const uint32_t* __restrict__ outbuf) {
  const int m = blockIdx.y;
  uint32_t* W = ws + (size_t)m * MAT_WORDS;
  const uint2* __restrict__ seg = (const uint2*)(outbuf + (size_t)m * 16777216u) + (size_t)blockIdx.x * SEGCAP;
  __shared__ uint32_t h[2048 * 4];
  for (int i = threadIdx.x; i < 2048 * 4; i += blockDim.x) h[i] = 0u;
  uint32_t n = W[OFF_BCNT + blockIdx.x];
  uint32_t p21 = W[OFF_PREFIX] >> 21;
  __syncthreads();
  const uint32_t sub = threadIdx.x & 3u;
  for (uint32_t e = threadIdx.x; e < n; e += blockDim.x) {
    uint2 v = seg[e];
    if ((v.y >> 21) == p21) atomicAdd(&h[((v.y >> 10) & 2047u) * 4u + sub], 1u);
  }
  __syncthreads();
  for (int b = threadIdx.x; b < 2048; b += blockDim.x) {
    uint32_t s = h[b * 4] + h[b * 4 + 1] + h[b * 4 + 2] + h[b * 4 + 3];
    if (s) atomicAdd(&W[OFF_H2 + b], s);
  }
}

__global__ void scan2_k(uint32_t* __restrict__ ws) {
  const int m = blockIdx.x;
  uint32_t* W = ws + (size_t)m * MAT_WORDS;
  __shared__ uint32_t h[2048];
  __shared__ uint32_t ps[256];
  const int t = threadIdx.x;
  uint32_t r = W[OFF_RANK];
  uint32_t prefix = W[OFF_PREFIX];
  uint32_t s = 0u;
  for (int k = 0; k < 8; k++) {
    int b = t * 8 + k;
    uint32_t v = W[OFF_H2 + b];
    h[b] = v; s += v;
  }
  ps[t] = s;
  __syncthreads();
  for (int off = 1; off < 256; off <<= 1) {
    uint32_t v = (t >= off) ? ps[t - off] : 0u;
    __syncthreads();
    ps[t] += v;
    __syncthreads();
  }
  uint32_t base = (t == 0) ? 0u : ps[t - 1];
  for (int k = 0; k < 8; k++) {
    int b = t * 8 + k;
    uint32_t c = h[b];
    if (r >= base && r < base + c) {
      W[OFF_PREFIX] = prefix | ((uint32_t)b << 10);
      W[OFF_RANK]   = r - base;
    }
    base += c;
  }
}

// Buffer pass: low-10-bit histogram + exact tie-candidate collection.
__global__ void pass3b_k(uint32_t* __restrict__ ws, const uint32_t* __restrict__ outbuf) {
  const int m = blockIdx.y;
  uint32_t* W = ws + (size_t)m * MAT_WORDS;
  const uint2* __restrict__ seg = (const uint2*)(outbuf + (size_t)m * 16777216u) + (size_t)blockIdx.x * SEGCAP;
  __shared__ uint32_t h[1024];
  for (int i = threadIdx.x; i < 1024; i += blockDim.x) h[i] = 0u;
  uint32_t n = W[OFF_BCNT + blockIdx.x];
  uint32_t p10 = W[OFF_PREFIX] >> 10;
  __syncthreads();
  for (uint32_t e = threadIdx.x; e < n; e += blockDim.x) {
    uint2 v = seg[e];
    if ((v.y >> 10) == p10) {
      atomicAdd(&h[v.y & 1023u], 1u);
      uint32_t slot = atomicAdd(&W[OFF_TCNT], 1u);   // ~1-4K total per matrix
      if (slot < TCAP) { W[OFF_TBUF + 2u * slot] = v.x; W[OFF_TBUF + 2u * slot + 1u] = v.y; }
    }
  }
  __syncthreads();
  for (int b = threadIdx.x; b < 1024; b += blockDim.x)
    if (h[b]) atomicAdd(&W[OFF_H3 + b], h[b]);
}

// Fused: scan H3 -> T, then tie-resolve entirely in LDS (verified since R1).
__global__ void scan3tie_k(uint32_t* __restrict__ ws) {
  const int m = blockIdx.x;
  uint32_t* W = ws + (size_t)m * MAT_WORDS;
  __shared__ uint32_t h[1024];
  __shared__ uint32_t ps[256];
  __shared__ uint32_t sT, sTarget;
  __shared__ uint32_t tie_idx[1024];
  __shared__ uint32_t tie_n;
  const int t = threadIdx.x;
  uint32_t r = W[OFF_RANK];
  uint32_t prefix = W[OFF_PREFIX];
  uint32_t cnt = W[OFF_TCNT]; if (cnt > TCAP) cnt = TCAP;
  if (t == 0) tie_n = 0u;
  uint32_t s = 0u;
  for (int k = 0; k < 4; k++) {
    int b = t * 4 + k;
    uint32_t v = W[OFF_H3 + b];
    h[b] = v; s += v;
  }
  ps[t] = s;
  __syncthreads();
  for (int off = 1; off < 256; off <<= 1) {
    uint32_t v = (t >= off) ? ps[t - off] : 0u;
    __syncthreads();
    ps[t] += v;
    __syncthreads();
  }
  uint32_t base = (t == 0) ? 0u : ps[t - 1];
  for (int k = 0; k < 4; k++) {
    int b = t * 4 + k;
    uint32_t c = h[b];
    if (r >= base && r < base + c) { sT = prefix | (uint32_t)b; sTarget = r - base; }
    base += c;
  }
  __syncthreads();
  const uint32_t T = sT, target = sTarget;       // target = p; q = E - p get 1
  for (uint32_t c2 = t; c2 < cnt; c2 += 256u) {
    if (W[OFF_TBUF + 2u * c2 + 1u] == T) {
      uint32_t slot = atomicAdd(&tie_n, 1u);
      if (slot < 1024u) tie_idx[slot] = W[OFF_TBUF + 2u * c2];
    }
  }
  __syncthreads();
  uint32_t E2 = tie_n; if (E2 > 1024u) E2 = 1024u;
  for (uint32_t c2 = t; c2 < E2; c2 += 256u) {
    uint32_t xi = tie_idx[c2];
    uint32_t lt = 0u;
    for (uint32_t k2 = 0; k2 < E2; k2++) lt += (tie_idx[k2] < xi) ? 1u : 0u;
    if (lt == target) W[OFF_C] = xi;             // p-th smallest index = cutoff
  }
  if (t == 0) W[OFF_T] = T;
}

__global__ void mask_k(const float* __restrict__ A, const float* __restrict__ B,
                       float* __restrict__ out, const uint32_t* __restrict__ ws,
                       int nvec, int n) {
  const int m = blockIdx.y;
  const float4* __restrict__ src = (const float4*)(m == 0 ? A : B);
  float4* __restrict__ dst = (float4*)(out + (size_t)m * (size_t)n);
  const uint32_t* W = ws + (size_t)m * MAT_WORDS;
  const uint32_t T = W[OFF_T];
  const uint32_t C = W[OFF_C];
  int idx0 = blockIdx.x * blockDim.x + threadIdx.x;
  int stride = gridDim.x * blockDim.x;
  for (int i = idx0; i < nvec; i += stride) {
    float4 f = src[i];
    const float v[4] = {f.x, f.y, f.z, f.w};
    float r[4];
#pragma unroll
    for (int c = 0; c < 4; c++) {
      uint32_t u = __float_as_uint(v[c]) & 0x7fffffffu;
      uint32_t idx = (uint32_t)i * 4u + (uint32_t)c;
      r[c] = (u > T || (u == T && idx >= C)) ? 1.0f : 0.0f;
    }
    dst[i] = make_float4(r[0], r[1], r[2], r[3]);
  }
}

extern "C" void kernel_launch(void* const* d_in, const int* in_sizes, int n_in,
                              void* d_out, int out_size, void* d_ws, size_t ws_size,
                              hipStream_t stream) {
  const float* A = (const float*)d_in[0];
  const float* B = (const float*)d_in[1];
  float* out = (float*)d_out;
  uint32_t* ws = (uint32_t*)d_ws;
  uint32_t* outbuf = (uint32_t*)d_out;       // scratch until mask_k overwrites it
  const int n = in_sizes[0];                 // 16777216 per matrix
  const int nvec = n / 4;
  const uint32_t j = (uint32_t)((1.0 - 0.1) * (double)n);  // Python int((1-k)*n)
  const uint32_t keep = (uint32_t)n - j;                   // 1677722
  const uint32_t need = (13u * 65536u) / 100u;             // 13% sample quantile

  init_k<<<(INIT_WORDS + 255) / 256, 256, 0, stream>>>(ws);
  sample_k<<<dim3(16, 2), 256, 0, stream>>>(A, B, ws, nvec);
  scanG_k<<<2, 256, 0, stream>>>(ws, need);
  compact_k<<<dim3(NB, 2), 256, 0, stream>>>(A, B, ws, outbuf, nvec);
  hist1b_k<<<dim3(NB, 2), 256, 0, stream>>>(ws, outbuf);
  scan1_k<<<2, 256, 0, stream>>>(ws, keep);
  hist2b_k<<<dim3(NB, 2), 256, 0, stream>>>(ws, outbuf);
  scan2_k<<<2, 256, 0, stream>>>(ws);
  pass3b_k<<<dim3(NB, 2), 256, 0, stream>>>(ws, outbuf);
  scan3tie_k<<<2, 256, 0, stream>>>(ws);
  mask_k<<<dim3(2048, 2), 256, 0, stream>>>(A, B, out, ws, nvec, n);
}